// Round 1
// 109.598 us; speedup vs baseline: 1.0182x; 1.0182x over previous
//
#include <hip/hip_runtime.h>
#include <math.h>

#define NHID 512
#define T_K  256
#define T_Q  128
#define BB   8

// tanh(x) = 1 - 2/(exp2(C*x)+1), C = 2*log2(e)
constexpr float C2L2E = 2.8853900817779268f;
constexpr float L2E   = 1.4426950408889634f;

__device__ __forceinline__ float fexp2(float x) { return __builtin_amdgcn_exp2f(x); }
__device__ __forceinline__ float frcp(float x)  { return __builtin_amdgcn_rcpf(x); }

typedef __attribute__((ext_vector_type(8))) short bf16x8;
typedef __attribute__((ext_vector_type(4))) float f32x4;

__device__ __forceinline__ unsigned short f2bf(float x) {
    unsigned u = __builtin_bit_cast(unsigned, x);
    unsigned r = (u + 0x7FFFu + ((u >> 16) & 1u)) >> 16;
    return (unsigned short)r;
}
__device__ __forceinline__ float bf2f(unsigned short h) {
    unsigned u = ((unsigned)h) << 16;
    return __builtin_bit_cast(float, u);
}
__device__ __forceinline__ unsigned packbf(float a, float b) {
    return (unsigned)f2bf(a) | ((unsigned)f2bf(b) << 16);
}
__device__ __forceinline__ float lo16(unsigned u) {
    return __builtin_bit_cast(float, u << 16);
}
__device__ __forceinline__ float hi16(unsigned u) {
    return __builtin_bit_cast(float, u & 0xFFFF0000u);
}

// ---------------------------------------------------------------------------
// Kernel 1: proj GEMM, in-kernel W1 transpose/split, free ckp emission.
// (UNCHANGED this round for clean attribution of the scoreav change.)
// ---------------------------------------------------------------------------
__global__ __launch_bounds__(256) void proj_kernel(
    const float* __restrict__ qry, const float* __restrict__ ckey,
    const float* __restrict__ W1, const float* __restrict__ b1,
    uint4* __restrict__ ekto, float* __restrict__ eq,
    unsigned int* __restrict__ ckp)
{
    const int row0 = blockIdx.x * 32;
    const int col0 = blockIdx.y * 64;
    const bool isK = row0 < 2048;
    const int bhalf = isK ? 0 : 512;

    __shared__ __align__(16) unsigned short As_h[32 * 64];
    __shared__ __align__(16) unsigned short As_l[32 * 64];
    __shared__ __align__(16) unsigned short Bs_h[64 * 64];
    __shared__ __align__(16) unsigned short Bs_l[64 * 64];

    const int t    = threadIdx.x;
    const int wave = t >> 6;
    const int lane = t & 63;
    const int wm = (wave & 1) * 16;
    const int wn = (wave >> 1) * 32;

    f32x4 acc[2] = {};

    const int srA = t >> 3;
    const int scA = (t & 7) * 8;
    const float* gA = (isK ? ckey + (size_t)(row0 + srA) * 512
                           : qry  + (size_t)(row0 - 2048 + srA) * 512) + scA;
    const int swA = ((scA >> 3) ^ (srA & 7)) * 8;
    const bool emit_ckp = isK && (col0 == 0);
    const int rowA = row0 + srA;
    unsigned int* ckp_dst = emit_ckp
        ? ckp + ((size_t)(rowA & 7) * 256 + (rowA >> 3)) * 256
        : nullptr;

    const int nB = t & 63;
    const int kgB = wave * 16;
    const float* gB = W1 + (size_t)(bhalf + kgB) * 512 + col0 + nB;
    const int caB = wave * 2;
    const int swB0 = nB * 64 + (((caB + 0) ^ (nB & 7)) * 8);
    const int swB1 = nB * 64 + (((caB + 1) ^ (nB & 7)) * 8);

    const int quad = lane >> 4, fr = lane & 15;

    float4 pa0 = *(const float4*)&gA[0];
    float4 pa1 = *(const float4*)&gA[4];
    float bv[16];
    #pragma unroll
    for (int kk = 0; kk < 16; ++kk)
        bv[kk] = gB[(size_t)kk * 512];

    for (int k0 = 0; k0 < 512; k0 += 64) {
        float fa[8];
        *(float4*)&fa[0] = pa0; *(float4*)&fa[4] = pa1;
        union { uint4 v; unsigned short s[8]; } hA, lA, bh0, bh1, bl0, bl1;
        #pragma unroll
        for (int e = 0; e < 8; ++e) {
            const unsigned short hb = f2bf(fa[e]);
            hA.s[e] = hb; lA.s[e] = f2bf(fa[e] - bf2f(hb));
        }
        #pragma unroll
        for (int e = 0; e < 8; ++e) {
            const unsigned short hb = f2bf(bv[e]);
            bh0.s[e] = hb; bl0.s[e] = f2bf(bv[e] - bf2f(hb));
        }
        #pragma unroll
        for (int e = 0; e < 8; ++e) {
            const unsigned short hb = f2bf(bv[8 + e]);
            bh1.s[e] = hb; bl1.s[e] = f2bf(bv[8 + e] - bf2f(hb));
        }
        if (emit_ckp)
            *(uint4*)&ckp_dst[(k0 + scA) >> 1] = hA.v;

        __syncthreads();
        *(uint4*)&As_h[srA * 64 + swA] = hA.v;
        *(uint4*)&As_l[srA * 64 + swA] = lA.v;
        *(uint4*)&Bs_h[swB0] = bh0.v;  *(uint4*)&Bs_h[swB1] = bh1.v;
        *(uint4*)&Bs_l[swB0] = bl0.v;  *(uint4*)&Bs_l[swB1] = bl1.v;
        __syncthreads();

        if (k0 + 64 < 512) {
            pa0 = *(const float4*)&gA[k0 + 64];
            pa1 = *(const float4*)&gA[k0 + 68];
            #pragma unroll
            for (int kk = 0; kk < 16; ++kk)
                bv[kk] = gB[(size_t)(k0 + 64 + kk) * 512];
        }

        #pragma unroll
        for (int ks = 0; ks < 2; ++ks) {
            const int cchunk = ks * 4 + quad;
            const int m = wm + fr;
            const bf16x8 afh = *(const bf16x8*)&As_h[m * 64 + ((cchunk ^ (m & 7)) * 8)];
            const bf16x8 afl = *(const bf16x8*)&As_l[m * 64 + ((cchunk ^ (m & 7)) * 8)];
            bf16x8 bfh[2], bfl[2];
            #pragma unroll
            for (int nt = 0; nt < 2; ++nt) {
                const int n = wn + nt * 16 + fr;
                bfh[nt] = *(const bf16x8*)&Bs_h[n * 64 + ((cchunk ^ (n & 7)) * 8)];
                bfl[nt] = *(const bf16x8*)&Bs_l[n * 64 + ((cchunk ^ (n & 7)) * 8)];
            }
            #pragma unroll
            for (int nt = 0; nt < 2; ++nt) {
                acc[nt] = __builtin_amdgcn_mfma_f32_16x16x32_bf16(afh, bfh[nt], acc[nt], 0, 0, 0);
                acc[nt] = __builtin_amdgcn_mfma_f32_16x16x32_bf16(afh, bfl[nt], acc[nt], 0, 0, 0);
                acc[nt] = __builtin_amdgcn_mfma_f32_16x16x32_bf16(afl, bfh[nt], acc[nt], 0, 0, 0);
            }
        }
    }

    #pragma unroll
    for (int nt = 0; nt < 2; ++nt) {
        const int colg = col0 + wn + nt * 16 + fr;
        const float b1v = b1[colg];
        #pragma unroll
        for (int i = 0; i < 4; ++i) {
            const int rowg = row0 + wm + quad * 4 + i;
            const float v = acc[nt][i];
            if (isK) {
                const float e = fexp2((v + b1v) * C2L2E);
                const float ep = __shfl_xor(e, 1, 64);
                unsigned pk = ((fr & 1) == 0) ? packbf(e, ep) : packbf(ep, e);
                unsigned pk2 = __shfl_xor(pk, 2, 64);
                if (fr & 2) { unsigned tmp = pk; pk = pk2; pk2 = tmp; }
                const unsigned px  = __shfl_xor(pk, 4, 64);
                const unsigned px2 = __shfl_xor(pk2, 4, 64);
                if ((fr & 7) == 0) {
                    const int kidx = rowg >> 3;
                    const int bb   = rowg & 7;
                    const int ho   = colg >> 3;
                    ekto[((size_t)bb * 64 + ho) * 256 + kidx] =
                        make_uint4(pk, pk2, px, px2);
                }
            } else {
                eq[(size_t)(rowg - 2048) * 512 + colg] = fexp2(v * C2L2E);
            }
        }
    }
}

// ---------------------------------------------------------------------------
// Kernel 2: fused score + softmax + antvec.
// R16: score loop hand-unrolled with NAMED double-buffer registers LA0..3 /
// LB0..3 (rule #20: no runtime-indexed ext_vector arrays -> guaranteed VGPR,
// never scratch), every LDS offset now a compile-time immediate, and
// __launch_bounds__(512, 4) pins VGPR<=128 so 2 blocks/CU stay resident.
// Math per term is bit-identical to R15.
// ---------------------------------------------------------------------------
__global__ __launch_bounds__(512, 4) void scoreav_kernel(
    const uint4* __restrict__ ekto, const float* __restrict__ eq,
    const float* __restrict__ W2, const float* __restrict__ b2,
    const int* __restrict__ mask, const unsigned int* __restrict__ ckp,
    float* __restrict__ prob_out, float* __restrict__ out_ant)
{
    const int t    = threadIdx.x;
    const int lane = t & 63;
    const int wave = __builtin_amdgcn_readfirstlane(t >> 6);
    const int kk   = t & 255;
    const int half = t >> 8;
    const int q0   = blockIdx.x * 2;
    const int b    = blockIdx.y;

    __shared__ float eq0s[512], eq1s[512], w2s[512];   // 6 KB
    __shared__ float rp[2][512];                       // 4 KB
    __shared__ float ps[2][256];                       // 2 KB

    eq0s[t] = eq[((size_t)q0 * 8 + b) * 512 + t];
    eq1s[t] = eq[((size_t)(q0 + 1) * 8 + b) * 512 + t];
    w2s[t]  = W2[t];

    const float4 wA = *(const float4*)&W2[lane * 4];
    const float4 wB = *(const float4*)&W2[256 + lane * 4];
    float s2 = wA.x + wA.y + wA.z + wA.w + wB.x + wB.y + wB.z + wB.w;
    #pragma unroll
    for (int m = 32; m; m >>= 1) s2 += __shfl_xor(s2, m, 64);
    const float base = s2 + b2[0];
    __syncthreads();

    // ---- score: thread owns (k=kk, h-octets half*32..half*32+31) ----
    const uint4* __restrict__ ekb = ekto + (size_t)b * 64 * 256 + kk;
    float r0a = 0.f, r0b = 0.f, r1a = 0.f, r1b = 0.f;

    uint4 LA0, LA1, LA2, LA3, LB0, LB1, LB2, LB3;

#define PREF(D, G) \
    D##0 = ekb[(size_t)(half * 32 + (G) * 4 + 0) * 256]; \
    D##1 = ekb[(size_t)(half * 32 + (G) * 4 + 1) * 256]; \
    D##2 = ekb[(size_t)(half * 32 + (G) * 4 + 2) * 256]; \
    D##3 = ekb[(size_t)(half * 32 + (G) * 4 + 3) * 256];

#define JBODY(U, G, J) { \
    const int h = (half * 32 + (G) * 4 + (J)) * 8; \
    const float ek0 = lo16(U.x), ek1 = hi16(U.x); \
    const float ek2 = lo16(U.y), ek3 = hi16(U.y); \
    const float ek4 = lo16(U.z), ek5 = hi16(U.z); \
    const float ek6 = lo16(U.w), ek7 = hi16(U.w); \
    const float4 wL = *(const float4*)&w2s[h]; \
    const float4 wH = *(const float4*)&w2s[h + 4]; \
    { /* q0 */ \
        const float4 eL = *(const float4*)&eq0s[h]; \
        const float4 eH = *(const float4*)&eq0s[h + 4]; \
        { \
            const float a0 = fmaf(ek0, eL.x, 1.0f); \
            const float a1 = fmaf(ek1, eL.y, 1.0f); \
            const float a2 = fmaf(ek2, eL.z, 1.0f); \
            const float a3 = fmaf(ek3, eL.w, 1.0f); \
            const float d01 = a0 * a1, d23 = a2 * a3; \
            const float n01 = fmaf(wL.x, a1, wL.y * a0); \
            const float n23 = fmaf(wL.z, a3, wL.w * a2); \
            const float N = fmaf(n01, d23, n23 * d01); \
            r0a = fmaf(N, frcp(d01 * d23), r0a); \
        } \
        { \
            const float a0 = fmaf(ek4, eH.x, 1.0f); \
            const float a1 = fmaf(ek5, eH.y, 1.0f); \
            const float a2 = fmaf(ek6, eH.z, 1.0f); \
            const float a3 = fmaf(ek7, eH.w, 1.0f); \
            const float d01 = a0 * a1, d23 = a2 * a3; \
            const float n01 = fmaf(wH.x, a1, wH.y * a0); \
            const float n23 = fmaf(wH.z, a3, wH.w * a2); \
            const float N = fmaf(n01, d23, n23 * d01); \
            r0b = fmaf(N, frcp(d01 * d23), r0b); \
        } \
    } \
    { /* q1 */ \
        const float4 eL = *(const float4*)&eq1s[h]; \
        const float4 eH = *(const float4*)&eq1s[h + 4]; \
        { \
            const float a0 = fmaf(ek0, eL.x, 1.0f); \
            const float a1 = fmaf(ek1, eL.y, 1.0f); \
            const float a2 = fmaf(ek2, eL.z, 1.0f); \
            const float a3 = fmaf(ek3, eL.w, 1.0f); \
            const float d01 = a0 * a1, d23 = a2 * a3; \
            const float n01 = fmaf(wL.x, a1, wL.y * a0); \
            const float n23 = fmaf(wL.z, a3, wL.w * a2); \
            const float N = fmaf(n01, d23, n23 * d01); \
            r1a = fmaf(N, frcp(d01 * d23), r1a); \
        } \
        { \
            const float a0 = fmaf(ek4, eH.x, 1.0f); \
            const float a1 = fmaf(ek5, eH.y, 1.0f); \
            const float a2 = fmaf(ek6, eH.z, 1.0f); \
            const float a3 = fmaf(ek7, eH.w, 1.0f); \
            const float d01 = a0 * a1, d23 = a2 * a3; \
            const float n01 = fmaf(wH.x, a1, wH.y * a0); \
            const float n23 = fmaf(wH.z, a3, wH.w * a2); \
            const float N = fmaf(n01, d23, n23 * d01); \
            r1b = fmaf(N, frcp(d01 * d23), r1b); \
        } \
    } \
}

#define GROUP(D, G) JBODY(D##0, G, 0) JBODY(D##1, G, 1) JBODY(D##2, G, 2) JBODY(D##3, G, 3)

    PREF(LA, 0)
    PREF(LB, 1) GROUP(LA, 0)
    PREF(LA, 2) GROUP(LB, 1)
    PREF(LB, 3) GROUP(LA, 2)
    PREF(LA, 4) GROUP(LB, 3)
    PREF(LB, 5) GROUP(LA, 4)
    PREF(LA, 6) GROUP(LB, 5)
    PREF(LB, 7) GROUP(LA, 6)
                GROUP(LB, 7)

#undef GROUP
#undef JBODY
#undef PREF

    rp[0][t] = r0a + r0b;
    rp[1][t] = r1a + r1b;
    __syncthreads();

    if (t < 256) {
        const int msk = mask[t * 8 + b];
        float s0 = base - 2.0f * (rp[0][t] + rp[0][t + 256]);
        float s1 = base - 2.0f * (rp[1][t] + rp[1][t + 256]);
        if (msk) { s0 = -INFINITY; s1 = -INFINITY; }
        ps[0][t] = s0;
        ps[1][t] = s1;
    }
    __syncthreads();

    // ---- softmax: waves 0,1 ----
    if (wave < 2) {
        float4 sv = *(const float4*)&ps[wave][lane * 4];
        float m = fmaxf(fmaxf(sv.x, sv.y), fmaxf(sv.z, sv.w));
        #pragma unroll
        for (int d = 32; d; d >>= 1) m = fmaxf(m, __shfl_xor(m, d, 64));
        float4 pv;
        pv.x = fexp2((sv.x - m) * L2E);
        pv.y = fexp2((sv.y - m) * L2E);
        pv.z = fexp2((sv.z - m) * L2E);
        pv.w = fexp2((sv.w - m) * L2E);
        float sum = pv.x + pv.y + pv.z + pv.w;
        #pragma unroll
        for (int d = 32; d; d >>= 1) sum += __shfl_xor(sum, d, 64);
        const float inv = frcp(sum);
        pv.x *= inv; pv.y *= inv; pv.z *= inv; pv.w *= inv;
        *(float4*)&ps[wave][lane * 4] = pv;
        const int qb_idx = (q0 + wave) * 8 + b;
        const int kbase = lane * 4;
        prob_out[(size_t)(kbase + 0) * 1024 + qb_idx] = pv.x;
        prob_out[(size_t)(kbase + 1) * 1024 + qb_idx] = pv.y;
        prob_out[(size_t)(kbase + 2) * 1024 + qb_idx] = pv.z;
        prob_out[(size_t)(kbase + 3) * 1024 + qb_idx] = pv.w;
    }
    __syncthreads();

    // ---- antvec: wave -> 64 h; lane = (kq = lane>>3, hq = lane&7, 8 h) ----
    {
        const int kq = lane >> 3;          // 0..7 (k residue mod 8)
        const int hq = lane & 7;           // 0..7 (h-octet within wave's 64 h)
        const int pbase = wave * 32 + hq * 4;   // bf16-pair index
        const unsigned int* __restrict__ ckb = ckp + (size_t)b * 256 * 256;
        float4 a0q0 = {}, a1q0 = {}, a0q1 = {}, a1q1 = {};
        #pragma unroll 8
        for (int ki = 0; ki < 32; ++ki) {
            const int k = ki * 8 + kq;
            const uint4 U = *(const uint4*)&ckb[(size_t)k * 256 + pbase];
            const float c0 = lo16(U.x), c1 = hi16(U.x);
            const float c2 = lo16(U.y), c3 = hi16(U.y);
            const float c4 = lo16(U.z), c5 = hi16(U.z);
            const float c6 = lo16(U.w), c7 = hi16(U.w);
            const float p0 = ps[0][k];
            const float p1 = ps[1][k];
            a0q0.x = fmaf(p0, c0, a0q0.x); a0q0.y = fmaf(p0, c1, a0q0.y);
            a0q0.z = fmaf(p0, c2, a0q0.z); a0q0.w = fmaf(p0, c3, a0q0.w);
            a1q0.x = fmaf(p0, c4, a1q0.x); a1q0.y = fmaf(p0, c5, a1q0.y);
            a1q0.z = fmaf(p0, c6, a1q0.z); a1q0.w = fmaf(p0, c7, a1q0.w);
            a0q1.x = fmaf(p1, c0, a0q1.x); a0q1.y = fmaf(p1, c1, a0q1.y);
            a0q1.z = fmaf(p1, c2, a0q1.z); a0q1.w = fmaf(p1, c3, a0q1.w);
            a1q1.x = fmaf(p1, c4, a1q1.x); a1q1.y = fmaf(p1, c5, a1q1.y);
            a1q1.z = fmaf(p1, c6, a1q1.z); a1q1.w = fmaf(p1, c7, a1q1.w);
        }
        #pragma unroll
        for (int d = 8; d <= 32; d <<= 1) {
            a0q0.x += __shfl_xor(a0q0.x, d, 64); a0q0.y += __shfl_xor(a0q0.y, d, 64);
            a0q0.z += __shfl_xor(a0q0.z, d, 64); a0q0.w += __shfl_xor(a0q0.w, d, 64);
            a1q0.x += __shfl_xor(a1q0.x, d, 64); a1q0.y += __shfl_xor(a1q0.y, d, 64);
            a1q0.z += __shfl_xor(a1q0.z, d, 64); a1q0.w += __shfl_xor(a1q0.w, d, 64);
            a0q1.x += __shfl_xor(a0q1.x, d, 64); a0q1.y += __shfl_xor(a0q1.y, d, 64);
            a0q1.z += __shfl_xor(a0q1.z, d, 64); a0q1.w += __shfl_xor(a0q1.w, d, 64);
            a1q1.x += __shfl_xor(a1q1.x, d, 64); a1q1.y += __shfl_xor(a1q1.y, d, 64);
            a1q1.z += __shfl_xor(a1q1.z, d, 64); a1q1.w += __shfl_xor(a1q1.w, d, 64);
        }
        if (lane < 8) {
            const int h0 = wave * 64 + hq * 8;
            float* o0 = &out_ant[((size_t)q0 * 8 + b) * 512 + h0];
            float* o1 = &out_ant[((size_t)(q0 + 1) * 8 + b) * 512 + h0];
            *(float4*)&o0[0] = a0q0;  *(float4*)&o0[4] = a1q0;
            *(float4*)&o1[0] = a0q1;  *(float4*)&o1[4] = a1q1;
        }
    }
}

// ---------------------------------------------------------------------------
extern "C" void kernel_launch(void* const* d_in, const int* in_sizes, int n_in,
                              void* d_out, int out_size, void* d_ws, size_t ws_size,
                              hipStream_t stream)
{
    const float* qry  = (const float*)d_in[0];
    const float* ckey = (const float*)d_in[1];
    const int*   mask = (const int*)d_in[2];
    const float* W1   = (const float*)d_in[3];
    const float* b1   = (const float*)d_in[4];
    const float* W2   = (const float*)d_in[5];
    const float* b2   = (const float*)d_in[6];

    float* out_ant  = (float*)d_out;
    float* out_prob = (float*)d_out + T_Q * BB * NHID;

    float* ws = (float*)d_ws;
    uint4* ws_ekto = (uint4*)ws;                              // [8][64][256] uint4, 2MB
    float* ws_eq  = ws + 524288;                              // [1024][512] f32, 2MB
    unsigned int* ws_ckp = (unsigned int*)(ws + 1048576);     // [8][256][256] u32, 2MB

    proj_kernel<<<dim3(96, 8), 256, 0, stream>>>(qry, ckey, W1, b1,
                                                 ws_ekto, ws_eq, ws_ckp);
    scoreav_kernel<<<dim3(64, 8), 512, 0, stream>>>(ws_ekto, ws_eq, W2, b2, mask, ws_ckp,
                                                    out_prob, out_ant);
}

// Round 2
// 109.446 us; speedup vs baseline: 1.0196x; 1.0014x over previous
//
#include <hip/hip_runtime.h>
#include <math.h>

#define NHID 512
#define T_K  256
#define T_Q  128
#define BB   8

// tanh(x) = 1 - 2/(exp2(C*x)+1), C = 2*log2(e)
constexpr float C2L2E = 2.8853900817779268f;
constexpr float L2E   = 1.4426950408889634f;

__device__ __forceinline__ float fexp2(float x) { return __builtin_amdgcn_exp2f(x); }
__device__ __forceinline__ float frcp(float x)  { return __builtin_amdgcn_rcpf(x); }

typedef __attribute__((ext_vector_type(8))) short bf16x8;
typedef __attribute__((ext_vector_type(4))) float f32x4;
typedef __attribute__((ext_vector_type(2))) float f32x2;
typedef __attribute__((ext_vector_type(4))) float f32x4v;

__device__ __forceinline__ f32x2 fma2(f32x2 a, f32x2 b, f32x2 c) {
    return __builtin_elementwise_fma(a, b, c);
}

__device__ __forceinline__ unsigned short f2bf(float x) {
    unsigned u = __builtin_bit_cast(unsigned, x);
    unsigned r = (u + 0x7FFFu + ((u >> 16) & 1u)) >> 16;
    return (unsigned short)r;
}
__device__ __forceinline__ float bf2f(unsigned short h) {
    unsigned u = ((unsigned)h) << 16;
    return __builtin_bit_cast(float, u);
}
__device__ __forceinline__ unsigned packbf(float a, float b) {
    return (unsigned)f2bf(a) | ((unsigned)f2bf(b) << 16);
}
__device__ __forceinline__ float lo16(unsigned u) {
    return __builtin_bit_cast(float, u << 16);
}
__device__ __forceinline__ float hi16(unsigned u) {
    return __builtin_bit_cast(float, u & 0xFFFF0000u);
}

// ---------------------------------------------------------------------------
// Kernel 1: proj GEMM, in-kernel W1 transpose/split, free ckp emission.
// (UNCHANGED again this round for clean attribution of the scoreav change.)
// ---------------------------------------------------------------------------
__global__ __launch_bounds__(256) void proj_kernel(
    const float* __restrict__ qry, const float* __restrict__ ckey,
    const float* __restrict__ W1, const float* __restrict__ b1,
    uint4* __restrict__ ekto, float* __restrict__ eq,
    unsigned int* __restrict__ ckp)
{
    const int row0 = blockIdx.x * 32;
    const int col0 = blockIdx.y * 64;
    const bool isK = row0 < 2048;
    const int bhalf = isK ? 0 : 512;

    __shared__ __align__(16) unsigned short As_h[32 * 64];
    __shared__ __align__(16) unsigned short As_l[32 * 64];
    __shared__ __align__(16) unsigned short Bs_h[64 * 64];
    __shared__ __align__(16) unsigned short Bs_l[64 * 64];

    const int t    = threadIdx.x;
    const int wave = t >> 6;
    const int lane = t & 63;
    const int wm = (wave & 1) * 16;
    const int wn = (wave >> 1) * 32;

    f32x4 acc[2] = {};

    const int srA = t >> 3;
    const int scA = (t & 7) * 8;
    const float* gA = (isK ? ckey + (size_t)(row0 + srA) * 512
                           : qry  + (size_t)(row0 - 2048 + srA) * 512) + scA;
    const int swA = ((scA >> 3) ^ (srA & 7)) * 8;
    const bool emit_ckp = isK && (col0 == 0);
    const int rowA = row0 + srA;
    unsigned int* ckp_dst = emit_ckp
        ? ckp + ((size_t)(rowA & 7) * 256 + (rowA >> 3)) * 256
        : nullptr;

    const int nB = t & 63;
    const int kgB = wave * 16;
    const float* gB = W1 + (size_t)(bhalf + kgB) * 512 + col0 + nB;
    const int caB = wave * 2;
    const int swB0 = nB * 64 + (((caB + 0) ^ (nB & 7)) * 8);
    const int swB1 = nB * 64 + (((caB + 1) ^ (nB & 7)) * 8);

    const int quad = lane >> 4, fr = lane & 15;

    float4 pa0 = *(const float4*)&gA[0];
    float4 pa1 = *(const float4*)&gA[4];
    float bv[16];
    #pragma unroll
    for (int kk = 0; kk < 16; ++kk)
        bv[kk] = gB[(size_t)kk * 512];

    for (int k0 = 0; k0 < 512; k0 += 64) {
        float fa[8];
        *(float4*)&fa[0] = pa0; *(float4*)&fa[4] = pa1;
        union { uint4 v; unsigned short s[8]; } hA, lA, bh0, bh1, bl0, bl1;
        #pragma unroll
        for (int e = 0; e < 8; ++e) {
            const unsigned short hb = f2bf(fa[e]);
            hA.s[e] = hb; lA.s[e] = f2bf(fa[e] - bf2f(hb));
        }
        #pragma unroll
        for (int e = 0; e < 8; ++e) {
            const unsigned short hb = f2bf(bv[e]);
            bh0.s[e] = hb; bl0.s[e] = f2bf(bv[e] - bf2f(hb));
        }
        #pragma unroll
        for (int e = 0; e < 8; ++e) {
            const unsigned short hb = f2bf(bv[8 + e]);
            bh1.s[e] = hb; bl1.s[e] = f2bf(bv[8 + e] - bf2f(hb));
        }
        if (emit_ckp)
            *(uint4*)&ckp_dst[(k0 + scA) >> 1] = hA.v;

        __syncthreads();
        *(uint4*)&As_h[srA * 64 + swA] = hA.v;
        *(uint4*)&As_l[srA * 64 + swA] = lA.v;
        *(uint4*)&Bs_h[swB0] = bh0.v;  *(uint4*)&Bs_h[swB1] = bh1.v;
        *(uint4*)&Bs_l[swB0] = bl0.v;  *(uint4*)&Bs_l[swB1] = bl1.v;
        __syncthreads();

        if (k0 + 64 < 512) {
            pa0 = *(const float4*)&gA[k0 + 64];
            pa1 = *(const float4*)&gA[k0 + 68];
            #pragma unroll
            for (int kk = 0; kk < 16; ++kk)
                bv[kk] = gB[(size_t)(k0 + 64 + kk) * 512];
        }

        #pragma unroll
        for (int ks = 0; ks < 2; ++ks) {
            const int cchunk = ks * 4 + quad;
            const int m = wm + fr;
            const bf16x8 afh = *(const bf16x8*)&As_h[m * 64 + ((cchunk ^ (m & 7)) * 8)];
            const bf16x8 afl = *(const bf16x8*)&As_l[m * 64 + ((cchunk ^ (m & 7)) * 8)];
            bf16x8 bfh[2], bfl[2];
            #pragma unroll
            for (int nt = 0; nt < 2; ++nt) {
                const int n = wn + nt * 16 + fr;
                bfh[nt] = *(const bf16x8*)&Bs_h[n * 64 + ((cchunk ^ (n & 7)) * 8)];
                bfl[nt] = *(const bf16x8*)&Bs_l[n * 64 + ((cchunk ^ (n & 7)) * 8)];
            }
            #pragma unroll
            for (int nt = 0; nt < 2; ++nt) {
                acc[nt] = __builtin_amdgcn_mfma_f32_16x16x32_bf16(afh, bfh[nt], acc[nt], 0, 0, 0);
                acc[nt] = __builtin_amdgcn_mfma_f32_16x16x32_bf16(afh, bfl[nt], acc[nt], 0, 0, 0);
                acc[nt] = __builtin_amdgcn_mfma_f32_16x16x32_bf16(afl, bfh[nt], acc[nt], 0, 0, 0);
            }
        }
    }

    #pragma unroll
    for (int nt = 0; nt < 2; ++nt) {
        const int colg = col0 + wn + nt * 16 + fr;
        const float b1v = b1[colg];
        #pragma unroll
        for (int i = 0; i < 4; ++i) {
            const int rowg = row0 + wm + quad * 4 + i;
            const float v = acc[nt][i];
            if (isK) {
                const float e = fexp2((v + b1v) * C2L2E);
                const float ep = __shfl_xor(e, 1, 64);
                unsigned pk = ((fr & 1) == 0) ? packbf(e, ep) : packbf(ep, e);
                unsigned pk2 = __shfl_xor(pk, 2, 64);
                if (fr & 2) { unsigned tmp = pk; pk = pk2; pk2 = tmp; }
                const unsigned px  = __shfl_xor(pk, 4, 64);
                const unsigned px2 = __shfl_xor(pk2, 4, 64);
                if ((fr & 7) == 0) {
                    const int kidx = rowg >> 3;
                    const int bb   = rowg & 7;
                    const int ho   = colg >> 3;
                    ekto[((size_t)bb * 64 + ho) * 256 + kidx] =
                        make_uint4(pk, pk2, px, px2);
                }
            } else {
                eq[(size_t)(rowg - 2048) * 512 + colg] = fexp2(v * C2L2E);
            }
        }
    }
}

// ---------------------------------------------------------------------------
// Kernel 2: fused score + softmax + antvec.
// R17: (a) q-paired float2 math everywhere (targets v_pk_fma_f32 /
// v_pk_mul_f32 dual-f32 issue); (b) W2 reads in the score loop are
// wave-uniform (readfirstlane'd half) -> scalar s_load path, removing the
// w2 LDS broadcasts entirely; (c) eq staged as paired float2 (one b128 feeds
// 2h x 2q), cutting score-phase ds_read_b128 from 6 to 4 per octet.
// Per-component fma/rcp sequence is bit-identical to R16.
// ---------------------------------------------------------------------------
__global__ __launch_bounds__(512, 4) void scoreav_kernel(
    const uint4* __restrict__ ekto, const float* __restrict__ eq,
    const float* __restrict__ W2, const float* __restrict__ b2,
    const int* __restrict__ mask, const unsigned int* __restrict__ ckp,
    float* __restrict__ prob_out, float* __restrict__ out_ant)
{
    const int t    = threadIdx.x;
    const int lane = t & 63;
    const int wave = __builtin_amdgcn_readfirstlane(t >> 6);
    const int hu   = __builtin_amdgcn_readfirstlane(t >> 8);   // wave-uniform half
    const int kk   = t & 255;
    const int q0   = blockIdx.x * 2;
    const int b    = blockIdx.y;

    __shared__ __align__(16) f32x2 eqp[512];   // 4 KB  (eq q-pairs)
    __shared__ __align__(16) f32x2 rp2[512];   // 4 KB  (partial sums, q-paired)
    __shared__ float ps[2][256];               // 2 KB  (raw scores)
    __shared__ __align__(8) f32x2 ps2[256];    // 2 KB  (normalized probs, q-paired)

    {   // stage eq pairs
        const float* eqr0 = eq + ((size_t)q0 * 8 + b) * 512;
        const float* eqr1 = eq + ((size_t)(q0 + 1) * 8 + b) * 512;
        f32x2 ep; ep.x = eqr0[t]; ep.y = eqr1[t];
        eqp[t] = ep;
    }

    const float4 wA = *(const float4*)&W2[lane * 4];
    const float4 wB = *(const float4*)&W2[256 + lane * 4];
    float s2 = wA.x + wA.y + wA.z + wA.w + wB.x + wB.y + wB.z + wB.w;
    #pragma unroll
    for (int m = 32; m; m >>= 1) s2 += __shfl_xor(s2, m, 64);
    const float base = s2 + b2[0];
    __syncthreads();

    // ---- score: thread owns (k=kk, h-octets hu*32..hu*32+31), q-paired ----
    const uint4* __restrict__ ekb = ekto + (size_t)b * 64 * 256 + kk;
    const f32x2 one2 = {1.0f, 1.0f};
    f32x2 ra = {0.f, 0.f}, rb = {0.f, 0.f};

    uint4 LA0, LA1, LA2, LA3, LB0, LB1, LB2, LB3;

#define PREF(D, G) \
    D##0 = ekb[(size_t)(hu * 32 + (G) * 4 + 0) * 256]; \
    D##1 = ekb[(size_t)(hu * 32 + (G) * 4 + 1) * 256]; \
    D##2 = ekb[(size_t)(hu * 32 + (G) * 4 + 2) * 256]; \
    D##3 = ekb[(size_t)(hu * 32 + (G) * 4 + 3) * 256];

#define JBODY(U, G, J) { \
    const int hw = (hu * 32 + (G) * 4 + (J)) * 8; \
    const float ek0 = lo16(U.x), ek1 = hi16(U.x); \
    const float ek2 = lo16(U.y), ek3 = hi16(U.y); \
    const float ek4 = lo16(U.z), ek5 = hi16(U.z); \
    const float ek6 = lo16(U.w), ek7 = hi16(U.w); \
    const f32x4v E01 = *(const f32x4v*)&eqp[hw]; \
    const f32x4v E23 = *(const f32x4v*)&eqp[hw + 2]; \
    const f32x4v E45 = *(const f32x4v*)&eqp[hw + 4]; \
    const f32x4v E67 = *(const f32x4v*)&eqp[hw + 6]; \
    const float w0 = W2[hw + 0], w1 = W2[hw + 1]; \
    const float w2v = W2[hw + 2], w3 = W2[hw + 3]; \
    const float w4 = W2[hw + 4], w5 = W2[hw + 5]; \
    const float w6 = W2[hw + 6], w7 = W2[hw + 7]; \
    { \
        const f32x2 a0 = fma2((f32x2){ek0, ek0}, (f32x2){E01.x, E01.y}, one2); \
        const f32x2 a1 = fma2((f32x2){ek1, ek1}, (f32x2){E01.z, E01.w}, one2); \
        const f32x2 a2 = fma2((f32x2){ek2, ek2}, (f32x2){E23.x, E23.y}, one2); \
        const f32x2 a3 = fma2((f32x2){ek3, ek3}, (f32x2){E23.z, E23.w}, one2); \
        const f32x2 d01 = a0 * a1, d23 = a2 * a3; \
        const f32x2 n01 = fma2((f32x2){w0, w0}, a1, (f32x2){w1, w1} * a0); \
        const f32x2 n23 = fma2((f32x2){w2v, w2v}, a3, (f32x2){w3, w3} * a2); \
        const f32x2 N = fma2(n01, d23, n23 * d01); \
        const f32x2 D = d01 * d23; \
        const f32x2 R = {frcp(D.x), frcp(D.y)}; \
        ra = fma2(N, R, ra); \
    } \
    { \
        const f32x2 a0 = fma2((f32x2){ek4, ek4}, (f32x2){E45.x, E45.y}, one2); \
        const f32x2 a1 = fma2((f32x2){ek5, ek5}, (f32x2){E45.z, E45.w}, one2); \
        const f32x2 a2 = fma2((f32x2){ek6, ek6}, (f32x2){E67.x, E67.y}, one2); \
        const f32x2 a3 = fma2((f32x2){ek7, ek7}, (f32x2){E67.z, E67.w}, one2); \
        const f32x2 d01 = a0 * a1, d23 = a2 * a3; \
        const f32x2 n01 = fma2((f32x2){w4, w4}, a1, (f32x2){w5, w5} * a0); \
        const f32x2 n23 = fma2((f32x2){w6, w6}, a3, (f32x2){w7, w7} * a2); \
        const f32x2 N = fma2(n01, d23, n23 * d01); \
        const f32x2 D = d01 * d23; \
        const f32x2 R = {frcp(D.x), frcp(D.y)}; \
        rb = fma2(N, R, rb); \
    } \
}

#define GROUP(D, G) JBODY(D##0, G, 0) JBODY(D##1, G, 1) JBODY(D##2, G, 2) JBODY(D##3, G, 3)

    PREF(LA, 0)
    PREF(LB, 1) GROUP(LA, 0)
    PREF(LA, 2) GROUP(LB, 1)
    PREF(LB, 3) GROUP(LA, 2)
    PREF(LA, 4) GROUP(LB, 3)
    PREF(LB, 5) GROUP(LA, 4)
    PREF(LA, 6) GROUP(LB, 5)
    PREF(LB, 7) GROUP(LA, 6)
                GROUP(LB, 7)

#undef GROUP
#undef JBODY
#undef PREF

    rp2[t] = ra + rb;
    __syncthreads();

    if (t < 256) {
        const int msk = mask[t * 8 + b];
        const f32x2 rsum = rp2[t] + rp2[t + 256];
        float s0 = base - 2.0f * rsum.x;
        float s1 = base - 2.0f * rsum.y;
        if (msk) { s0 = -INFINITY; s1 = -INFINITY; }
        ps[0][t] = s0;
        ps[1][t] = s1;
    }
    __syncthreads();

    // ---- softmax: waves 0,1 (wave w handles q0+w) ----
    if (wave < 2) {
        float4 sv = *(const float4*)&ps[wave][lane * 4];
        float m = fmaxf(fmaxf(sv.x, sv.y), fmaxf(sv.z, sv.w));
        #pragma unroll
        for (int d = 32; d; d >>= 1) m = fmaxf(m, __shfl_xor(m, d, 64));
        float4 pv;
        pv.x = fexp2((sv.x - m) * L2E);
        pv.y = fexp2((sv.y - m) * L2E);
        pv.z = fexp2((sv.z - m) * L2E);
        pv.w = fexp2((sv.w - m) * L2E);
        float sum = pv.x + pv.y + pv.z + pv.w;
        #pragma unroll
        for (int d = 32; d; d >>= 1) sum += __shfl_xor(sum, d, 64);
        const float inv = frcp(sum);
        pv.x *= inv; pv.y *= inv; pv.z *= inv; pv.w *= inv;
        float* p2f = (float*)ps2;
        p2f[(lane * 4 + 0) * 2 + wave] = pv.x;
        p2f[(lane * 4 + 1) * 2 + wave] = pv.y;
        p2f[(lane * 4 + 2) * 2 + wave] = pv.z;
        p2f[(lane * 4 + 3) * 2 + wave] = pv.w;
        const int qb_idx = (q0 + wave) * 8 + b;
        const int kbase = lane * 4;
        prob_out[(size_t)(kbase + 0) * 1024 + qb_idx] = pv.x;
        prob_out[(size_t)(kbase + 1) * 1024 + qb_idx] = pv.y;
        prob_out[(size_t)(kbase + 2) * 1024 + qb_idx] = pv.z;
        prob_out[(size_t)(kbase + 3) * 1024 + qb_idx] = pv.w;
    }
    __syncthreads();

    // ---- antvec: wave -> 64 h; lane = (kq = lane>>3, hq = lane&7, 8 h),
    //      q-paired accumulators ----
    {
        const int kq = lane >> 3;
        const int hq = lane & 7;
        const int pbase = wave * 32 + hq * 4;
        const unsigned int* __restrict__ ckb = ckp + (size_t)b * 256 * 256;
        f32x2 a0 = {}, a1 = {}, a2 = {}, a3 = {}, a4 = {}, a5 = {}, a6 = {}, a7 = {};
        #pragma unroll 8
        for (int ki = 0; ki < 32; ++ki) {
            const int k = ki * 8 + kq;
            const uint4 U = *(const uint4*)&ckb[(size_t)k * 256 + pbase];
            const float c0 = lo16(U.x), c1 = hi16(U.x);
            const float c2 = lo16(U.y), c3 = hi16(U.y);
            const float c4 = lo16(U.z), c5 = hi16(U.z);
            const float c6 = lo16(U.w), c7 = hi16(U.w);
            const f32x2 p = ps2[k];
            a0 = fma2(p, (f32x2){c0, c0}, a0);
            a1 = fma2(p, (f32x2){c1, c1}, a1);
            a2 = fma2(p, (f32x2){c2, c2}, a2);
            a3 = fma2(p, (f32x2){c3, c3}, a3);
            a4 = fma2(p, (f32x2){c4, c4}, a4);
            a5 = fma2(p, (f32x2){c5, c5}, a5);
            a6 = fma2(p, (f32x2){c6, c6}, a6);
            a7 = fma2(p, (f32x2){c7, c7}, a7);
        }
        #pragma unroll
        for (int d = 8; d <= 32; d <<= 1) {
            a0.x += __shfl_xor(a0.x, d, 64); a0.y += __shfl_xor(a0.y, d, 64);
            a1.x += __shfl_xor(a1.x, d, 64); a1.y += __shfl_xor(a1.y, d, 64);
            a2.x += __shfl_xor(a2.x, d, 64); a2.y += __shfl_xor(a2.y, d, 64);
            a3.x += __shfl_xor(a3.x, d, 64); a3.y += __shfl_xor(a3.y, d, 64);
            a4.x += __shfl_xor(a4.x, d, 64); a4.y += __shfl_xor(a4.y, d, 64);
            a5.x += __shfl_xor(a5.x, d, 64); a5.y += __shfl_xor(a5.y, d, 64);
            a6.x += __shfl_xor(a6.x, d, 64); a6.y += __shfl_xor(a6.y, d, 64);
            a7.x += __shfl_xor(a7.x, d, 64); a7.y += __shfl_xor(a7.y, d, 64);
        }
        if (lane < 8) {
            const int h0 = wave * 64 + hq * 8;
            float* o0 = &out_ant[((size_t)q0 * 8 + b) * 512 + h0];
            float* o1 = &out_ant[((size_t)(q0 + 1) * 8 + b) * 512 + h0];
            o0[0] = a0.x; o0[1] = a1.x; o0[2] = a2.x; o0[3] = a3.x;
            o0[4] = a4.x; o0[5] = a5.x; o0[6] = a6.x; o0[7] = a7.x;
            o1[0] = a0.y; o1[1] = a1.y; o1[2] = a2.y; o1[3] = a3.y;
            o1[4] = a4.y; o1[5] = a5.y; o1[6] = a6.y; o1[7] = a7.y;
        }
    }
}

// ---------------------------------------------------------------------------
extern "C" void kernel_launch(void* const* d_in, const int* in_sizes, int n_in,
                              void* d_out, int out_size, void* d_ws, size_t ws_size,
                              hipStream_t stream)
{
    const float* qry  = (const float*)d_in[0];
    const float* ckey = (const float*)d_in[1];
    const int*   mask = (const int*)d_in[2];
    const float* W1   = (const float*)d_in[3];
    const float* b1   = (const float*)d_in[4];
    const float* W2   = (const float*)d_in[5];
    const float* b2   = (const float*)d_in[6];

    float* out_ant  = (float*)d_out;
    float* out_prob = (float*)d_out + T_Q * BB * NHID;

    float* ws = (float*)d_ws;
    uint4* ws_ekto = (uint4*)ws;                              // [8][64][256] uint4, 2MB
    float* ws_eq  = ws + 524288;                              // [1024][512] f32, 2MB
    unsigned int* ws_ckp = (unsigned int*)(ws + 1048576);     // [8][256][256] u32, 2MB

    proj_kernel<<<dim3(96, 8), 256, 0, stream>>>(qry, ckey, W1, b1,
                                                 ws_ekto, ws_eq, ws_ckp);
    scoreav_kernel<<<dim3(64, 8), 512, 0, stream>>>(ws_ekto, ws_eq, W2, b2, mask, ws_ckp,
                                                    out_prob, out_ant);
}